// Round 8
// baseline (133.762 us; speedup 1.0000x reference)
//
#include <hip/hip_runtime.h>
#include <hip/hip_bf16.h>

#define LN_EPS 1e-5f

typedef __attribute__((ext_vector_type(8))) short short8;
typedef __attribute__((ext_vector_type(4))) float floatx4;

static __device__ __forceinline__ unsigned int f2bfu(float f) {
    __hip_bfloat16 h = __float2bfloat16(f);
    return (unsigned int)__builtin_bit_cast(unsigned short, h);
}
static __device__ __forceinline__ float bf2f(unsigned short u) {
    return __builtin_bit_cast(float, (unsigned int)u << 16);
}

#define TA_P_STRIDE (257 * 512)   // tableA: [16][257][512] bf16; row 256 = zeros

// ---------------------------------------------------------------------------
// k_prep: blocks 0..511 cast up_w -> wb; 512..639 cast byte_emb -> bb;
// 640..655 zero tableA pad rows; 656..1679 transpose-cast pos_emb -> posT.
// ---------------------------------------------------------------------------
__global__ __launch_bounds__(256) void k_prep(
    const float* __restrict__ up_w, const float* __restrict__ byte_emb,
    const float* __restrict__ pos_emb,
    unsigned short* __restrict__ wb, unsigned short* __restrict__ bb,
    unsigned short* __restrict__ T, unsigned short* __restrict__ PT)
{
    const int b = blockIdx.x;
    if (b < 640) {
        const float* src;
        unsigned short* dst;
        int idx;
        if (b < 512) { src = up_w;     dst = wb; idx = (b * 256 + threadIdx.x) * 4; }
        else         { src = byte_emb; dst = bb; idx = ((b - 512) * 256 + threadIdx.x) * 4; }
        const float4 v = *(const float4*)&src[idx];
        ushort4 o;
        o.x = (unsigned short)f2bfu(v.x); o.y = (unsigned short)f2bfu(v.y);
        o.z = (unsigned short)f2bfu(v.z); o.w = (unsigned short)f2bfu(v.w);
        *(ushort4*)&dst[idx] = o;
    } else if (b < 656) {
        const int p = b - 640;
        if (threadIdx.x < 128) {
            ushort4 z; z.x = z.y = z.z = z.w = 0;
            *(ushort4*)&T[(size_t)p * TA_P_STRIDE + 256 * 512 + threadIdx.x * 4] = z;
        }
    } else {
        // transpose-cast: pos_emb [p][i][j] f32 -> posT [p][j][i] bf16
        const int idx = b - 656;
        const int j0 = (idx & 7) * 64;
        const int i0 = ((idx >> 3) & 7) * 64;
        const int p  = idx >> 6;
        const float* __restrict__ Pp = pos_emb + (size_t)p * 512 * 512;
        unsigned short* __restrict__ Tp = PT + (size_t)p * 512 * 512;

        __shared__ float S[64][65];
        const int r  = threadIdx.x >> 2;
        const int c0 = (threadIdx.x & 3) * 16;

        #pragma unroll
        for (int c = 0; c < 16; c += 4) {
            const float4 v = *(const float4*)&Pp[(size_t)(i0 + r) * 512 + j0 + c0 + c];
            S[r][c0 + c + 0] = v.x;
            S[r][c0 + c + 1] = v.y;
            S[r][c0 + c + 2] = v.z;
            S[r][c0 + c + 3] = v.w;
        }
        __syncthreads();

        #pragma unroll
        for (int h = 0; h < 2; ++h) {
            short8 o;
            #pragma unroll
            for (int k = 0; k < 8; ++k)
                o[k] = (short)f2bfu(S[c0 + h * 8 + k][r]);
            *(short8*)&Tp[(size_t)(j0 + r) * 512 + i0 + c0 + h * 8] = o;
        }
    }
}

// ---------------------------------------------------------------------------
// k1_d: tableA[p][m][j] = sum_i bb[m][i] * posT[p][j][i]  (bf16 MFMA)
// Block 256 thr = 4 waves (2x2), wave tile 32x32. Grid (8,4,16).
// ---------------------------------------------------------------------------
__global__ __launch_bounds__(256) void k1_d(
    const unsigned short* __restrict__ A,   // bb [256][512]
    const unsigned short* __restrict__ PT,  // posT [16][512][512] ([p][j][i])
    unsigned short* __restrict__ T)         // tableA [16][257][512]
{
    const int p  = blockIdx.z;
    const int j0 = blockIdx.x * 64;
    const int m0 = blockIdx.y * 64;
    const unsigned short* __restrict__ Bp = PT + (size_t)p * 512 * 512;
    unsigned short* __restrict__ Tp = T + (size_t)p * TA_P_STRIDE;

    const int tid = threadIdx.x;
    const int w   = tid >> 6, lane = tid & 63;
    const int lr  = lane & 15, lg = lane >> 4, lk = lg * 8;
    const int wr  = w >> 1, wc = w & 1;

    floatx4 acc[2][2] = {};

    #pragma unroll
    for (int k0 = 0; k0 < 512; k0 += 32) {
        short8 a[2], bfr[2];
        #pragma unroll
        for (int mf = 0; mf < 2; ++mf)
            a[mf] = *(const short8*)&A[(size_t)(m0 + wr * 32 + mf * 16 + lr) * 512 + k0 + lk];
        #pragma unroll
        for (int nf = 0; nf < 2; ++nf)
            bfr[nf] = *(const short8*)&Bp[(size_t)(j0 + wc * 32 + nf * 16 + lr) * 512 + k0 + lk];
        #pragma unroll
        for (int mf = 0; mf < 2; ++mf)
            #pragma unroll
            for (int nf = 0; nf < 2; ++nf)
                acc[mf][nf] = __builtin_amdgcn_mfma_f32_16x16x32_bf16(
                    a[mf], bfr[nf], acc[mf][nf], 0, 0, 0);
    }

    #pragma unroll
    for (int nf = 0; nf < 2; ++nf)
        #pragma unroll
        for (int mf = 0; mf < 2; ++mf)
            #pragma unroll
            for (int q = 0; q < 4; ++q)
                Tp[(size_t)(m0 + wr * 32 + mf * 16 + lg * 4 + q) * 512
                   + j0 + wc * 32 + nf * 16 + lr]
                    = (unsigned short)f2bfu(acc[mf][nf][q]);
}

// ---------------------------------------------------------------------------
// k_gather: e_pre[row][j] = sum_p tableA[p][idr(row,p)][j]  (fp32 accum, bf16
// out). One wave per row, 4 rows/block, 2048 blocks. Branchless via pad row.
// ---------------------------------------------------------------------------
__global__ __launch_bounds__(256) void k_gather(
    const int* __restrict__ ids,
    const unsigned short* __restrict__ T,
    unsigned short* __restrict__ e_pre)
{
    const int row  = blockIdx.x * 4 + (threadIdx.x >> 6);
    const int lane = threadIdx.x & 63;
    const int* __restrict__ idr = ids + row * 16;

    float acc[8] = {};
    #pragma unroll
    for (int p = 0; p < 16; ++p) {
        const int id = idr[p];
        const unsigned int off = (unsigned int)((p * 257 + (id < 0 ? 256 : id)) * 512);
        const short8 v = *(const short8*)&T[off + lane * 8];
        #pragma unroll
        for (int j = 0; j < 8; ++j)
            acc[j] += bf2f((unsigned short)v[j]);
    }
    short8 r;
    #pragma unroll
    for (int j = 0; j < 8; ++j) r[j] = (short)f2bfu(acc[j]);
    *(short8*)&e_pre[(size_t)row * 512 + lane * 8] = r;
}

// ---------------------------------------------------------------------------
// k_gemmln: out = LN(e_pre @ up_w^T + up_b), one block = 32 rows x 1024 cols.
// 1024 thr = 16 waves, wave tile 32x64 (acc[2][4]).
// Per K-step 32: B-tile 1024x32 staged into LDS via COALESCED loads (80B
// padded rows); T14: step k+1 global loads issued before step k's MFMAs.
// A-frags direct from e_pre (all waves share the same 32KB window -> L1).
// Epilogue: bias + fused row-LN.
// ---------------------------------------------------------------------------
__global__ __launch_bounds__(1024) void k_gemmln(
    const unsigned short* __restrict__ Aep,  // e_pre [8192][512] bf16
    const unsigned short* __restrict__ Wb,   // up_w  [1024][512] bf16
    const float* __restrict__ up_b,
    const float* __restrict__ gamma,
    const float* __restrict__ beta,
    float* __restrict__ out)                 // [8192][1024] f32
{
    extern __shared__ unsigned short B_lds[];   // [1024][40] shorts = 80 KB
    __shared__ float redS[32][17], redQ[32][17];

    const int r0   = blockIdx.x * 32;
    const int tid  = threadIdx.x;
    const int w    = tid >> 6, lane = tid & 63;
    const int lr   = lane & 15, lg = lane >> 4, lk = lg * 8;
    const int colb = w * 64;

    const int sq = tid & 3;        // 16B chunk within a col's 64B k-slice
    const int sc = tid >> 2;       // col 0..255 (+256*i)

    uint4 st[4];
    #define BGLOAD(step) do {                                                  \
        _Pragma("unroll")                                                      \
        for (int i = 0; i < 4; ++i)                                            \
            st[i] = *(const uint4*)&Wb[(size_t)(sc + 256 * i) * 512            \
                                       + (step) * 32 + sq * 8];                \
    } while (0)
    #define BSTORE() do {                                                      \
        _Pragma("unroll")                                                      \
        for (int i = 0; i < 4; ++i)                                            \
            *(uint4*)&B_lds[(sc + 256 * i) * 40 + sq * 8] = st[i];             \
    } while (0)

    BGLOAD(0);
    BSTORE();
    __syncthreads();

    floatx4 acc[2][4] = {};

    for (int step = 0; step < 16; ++step) {
        if (step < 15) BGLOAD(step + 1);

        short8 a[2], bfr[4];
        #pragma unroll
        for (int mf = 0; mf < 2; ++mf)
            a[mf] = *(const short8*)&Aep[(size_t)(r0 + mf * 16 + lr) * 512
                                         + step * 32 + lk];
        #pragma unroll
        for (int nf = 0; nf < 4; ++nf)
            bfr[nf] = *(const short8*)&B_lds[(colb + nf * 16 + lr) * 40 + lk];
        #pragma unroll
        for (int mf = 0; mf < 2; ++mf)
            #pragma unroll
            for (int nf = 0; nf < 4; ++nf)
                acc[mf][nf] = __builtin_amdgcn_mfma_f32_16x16x32_bf16(
                    a[mf], bfr[nf], acc[mf][nf], 0, 0, 0);

        __syncthreads();                       // all B_lds reads done
        if (step < 15) {
            BSTORE();
            __syncthreads();                   // writes visible
        }
    }
    #undef BGLOAD
    #undef BSTORE

    // bias
    #pragma unroll
    for (int nf = 0; nf < 4; ++nf) {
        const float bias = up_b[colb + nf * 16 + lr];
        #pragma unroll
        for (int mf = 0; mf < 2; ++mf)
            #pragma unroll
            for (int q = 0; q < 4; ++q)
                acc[mf][nf][q] += bias;
    }

    // LayerNorm: 16-lane-group reduce, then cross-wave LDS reduce
    float s[2][4], ss[2][4];
    #pragma unroll
    for (int mf = 0; mf < 2; ++mf)
        #pragma unroll
        for (int q = 0; q < 4; ++q) {
            float t1 = 0.0f, t2 = 0.0f;
            #pragma unroll
            for (int nf = 0; nf < 4; ++nf) {
                const float v = acc[mf][nf][q];
                t1 += v; t2 += v * v;
            }
            #pragma unroll
            for (int off = 1; off < 16; off <<= 1) {
                t1 += __shfl_xor(t1, off, 16);
                t2 += __shfl_xor(t2, off, 16);
            }
            s[mf][q] = t1; ss[mf][q] = t2;
        }

    if (lr == 0) {
        #pragma unroll
        for (int mf = 0; mf < 2; ++mf)
            #pragma unroll
            for (int q = 0; q < 4; ++q) {
                const int row = mf * 16 + lg * 4 + q;
                redS[row][w] = s[mf][q];
                redQ[row][w] = ss[mf][q];
            }
    }
    __syncthreads();

    float mu[2][4], rs[2][4];
    #pragma unroll
    for (int mf = 0; mf < 2; ++mf)
        #pragma unroll
        for (int q = 0; q < 4; ++q) {
            const int row = mf * 16 + lg * 4 + q;
            float S = 0.0f, SS = 0.0f;
            #pragma unroll
            for (int ww = 0; ww < 16; ++ww) { S += redS[row][ww]; SS += redQ[row][ww]; }
            const float m  = S * (1.0f / 1024.0f);
            const float vr = SS * (1.0f / 1024.0f) - m * m;
            mu[mf][q] = m;
            rs[mf][q] = rsqrtf(vr + LN_EPS);
        }

    #pragma unroll
    for (int nf = 0; nf < 4; ++nf) {
        const int col = colb + nf * 16 + lr;
        const float g  = gamma[col];
        const float be = beta[col];
        #pragma unroll
        for (int mf = 0; mf < 2; ++mf)
            #pragma unroll
            for (int q = 0; q < 4; ++q) {
                const int row = mf * 16 + lg * 4 + q;
                out[(size_t)(r0 + row) * 1024 + col]
                    = (acc[mf][nf][q] - mu[mf][q]) * rs[mf][q] * g + be;
            }
    }
}

extern "C" void kernel_launch(void* const* d_in, const int* in_sizes, int n_in,
                              void* d_out, int out_size, void* d_ws, size_t ws_size,
                              hipStream_t stream) {
    const int*   ids      = (const int*)d_in[0];
    const float* byte_emb = (const float*)d_in[1];
    const float* pos_emb  = (const float*)d_in[2];
    const float* up_w     = (const float*)d_in[3];
    const float* up_b     = (const float*)d_in[4];
    const float* gamma    = (const float*)d_in[5];
    const float* beta     = (const float*)d_in[6];
    float* out = (float*)d_out;

    // ws: wb 1MB | bb 0.25MB | posT 8MB | tableA ~4.2MB | e_pre 8MB
    unsigned short* wb     = (unsigned short*)d_ws;
    unsigned short* bb     = wb + (size_t)1024 * 512;
    unsigned short* posT   = bb + (size_t)256 * 512;
    unsigned short* tableA = posT + (size_t)16 * 512 * 512;
    unsigned short* e_pre  = tableA + (size_t)16 * TA_P_STRIDE;

    const int rows = in_sizes[0] / 16;   // 8192

    k_prep<<<1680, 256, 0, stream>>>(up_w, byte_emb, pos_emb, wb, bb, tableA, posT);

    dim3 g1(8, 4, 16);
    k1_d<<<g1, 256, 0, stream>>>(bb, posT, tableA);

    k_gather<<<rows / 4, 256, 0, stream>>>(ids, tableA, e_pre);

    k_gemmln<<<rows / 32, 1024, 1024 * 40 * sizeof(unsigned short), stream>>>(
        e_pre, wb, up_b, gamma, beta, out);
}

// Round 9
// 105.654 us; speedup vs baseline: 1.2660x; 1.2660x over previous
//
#include <hip/hip_runtime.h>
#include <hip/hip_bf16.h>

#define LN_EPS 1e-5f

typedef __attribute__((ext_vector_type(8))) short short8;
typedef __attribute__((ext_vector_type(4))) float floatx4;

static __device__ __forceinline__ unsigned int f2bfu(float f) {
    __hip_bfloat16 h = __float2bfloat16(f);
    return (unsigned int)__builtin_bit_cast(unsigned short, h);
}
static __device__ __forceinline__ float bf2f(unsigned short u) {
    return __builtin_bit_cast(float, (unsigned int)u << 16);
}

#define TA_P_STRIDE (257 * 512)   // tableA: [16][257][512] bf16; row 256 = zeros

// ---------------------------------------------------------------------------
// k_prep: blocks 0..511 cast up_w -> wb; 512..639 cast byte_emb -> bb;
// 640..655 zero tableA pad rows; 656..1679 transpose-cast pos_emb -> posT.
// ---------------------------------------------------------------------------
__global__ __launch_bounds__(256) void k_prep(
    const float* __restrict__ up_w, const float* __restrict__ byte_emb,
    const float* __restrict__ pos_emb,
    unsigned short* __restrict__ wb, unsigned short* __restrict__ bb,
    unsigned short* __restrict__ T, unsigned short* __restrict__ PT)
{
    const int b = blockIdx.x;
    if (b < 640) {
        const float* src;
        unsigned short* dst;
        int idx;
        if (b < 512) { src = up_w;     dst = wb; idx = (b * 256 + threadIdx.x) * 4; }
        else         { src = byte_emb; dst = bb; idx = ((b - 512) * 256 + threadIdx.x) * 4; }
        const float4 v = *(const float4*)&src[idx];
        ushort4 o;
        o.x = (unsigned short)f2bfu(v.x); o.y = (unsigned short)f2bfu(v.y);
        o.z = (unsigned short)f2bfu(v.z); o.w = (unsigned short)f2bfu(v.w);
        *(ushort4*)&dst[idx] = o;
    } else if (b < 656) {
        const int p = b - 640;
        if (threadIdx.x < 128) {
            ushort4 z; z.x = z.y = z.z = z.w = 0;
            *(ushort4*)&T[(size_t)p * TA_P_STRIDE + 256 * 512 + threadIdx.x * 4] = z;
        }
    } else {
        // transpose-cast: pos_emb [p][i][j] f32 -> posT [p][j][i] bf16
        const int idx = b - 656;
        const int j0 = (idx & 7) * 64;
        const int i0 = ((idx >> 3) & 7) * 64;
        const int p  = idx >> 6;
        const float* __restrict__ Pp = pos_emb + (size_t)p * 512 * 512;
        unsigned short* __restrict__ Tp = PT + (size_t)p * 512 * 512;

        __shared__ float S[64][65];
        const int r  = threadIdx.x >> 2;
        const int c0 = (threadIdx.x & 3) * 16;

        #pragma unroll
        for (int c = 0; c < 16; c += 4) {
            const float4 v = *(const float4*)&Pp[(size_t)(i0 + r) * 512 + j0 + c0 + c];
            S[r][c0 + c + 0] = v.x;
            S[r][c0 + c + 1] = v.y;
            S[r][c0 + c + 2] = v.z;
            S[r][c0 + c + 3] = v.w;
        }
        __syncthreads();

        #pragma unroll
        for (int h = 0; h < 2; ++h) {
            short8 o;
            #pragma unroll
            for (int k = 0; k < 8; ++k)
                o[k] = (short)f2bfu(S[c0 + h * 8 + k][r]);
            *(short8*)&Tp[(size_t)(j0 + r) * 512 + i0 + c0 + h * 8] = o;
        }
    }
}

// ---------------------------------------------------------------------------
// Shared m97-style GEMM body macros.
// Block 256 thr = 4 waves (2x2), BM=BN=128, BK=64, both operands K-major with
// row stride 512. Coalesced reg-staging -> linear LDS, ds_read_b128 frags,
// 2 barriers/iter, next-tile loads issued before MFMAs (T14).
// ---------------------------------------------------------------------------
#define GEMM_PROLOG()                                                          \
    __shared__ unsigned short As[128 * 64];                                    \
    __shared__ unsigned short Bs[128 * 64];                                    \
    const int tid = threadIdx.x;                                               \
    const int w   = tid >> 6, lane = tid & 63;                                 \
    const int lr  = lane & 15, lg = lane >> 4, lk = lg * 8;                    \
    const int wr  = w >> 1, wc = w & 1;                                        \
    const int srow = tid >> 3, schunk = (tid & 7) * 8;                         \
    uint4 ra[4], rb[4];                                                        \
    floatx4 acc[4][4] = {};

#define GEMM_LOAD(kt)                                                          \
    _Pragma("unroll")                                                          \
    for (int i = 0; i < 4; ++i) {                                              \
        ra[i] = *(const uint4*)&Ag[(size_t)(i * 32 + srow) * 512 + (kt) * 64 + schunk]; \
        rb[i] = *(const uint4*)&Bg[(size_t)(i * 32 + srow) * 512 + (kt) * 64 + schunk]; \
    }

#define GEMM_STORE()                                                           \
    _Pragma("unroll")                                                          \
    for (int i = 0; i < 4; ++i) {                                              \
        *(uint4*)&As[(i * 32 + srow) * 64 + schunk] = ra[i];                   \
        *(uint4*)&Bs[(i * 32 + srow) * 64 + schunk] = rb[i];                   \
    }

#define GEMM_MAIN()                                                            \
    GEMM_LOAD(0);                                                              \
    for (int kt = 0; kt < 8; ++kt) {                                           \
        __syncthreads();                                                       \
        GEMM_STORE();                                                          \
        __syncthreads();                                                       \
        if (kt < 7) { GEMM_LOAD(kt + 1); }                                     \
        _Pragma("unroll")                                                      \
        for (int kk = 0; kk < 2; ++kk) {                                       \
            short8 af[4], bf[4];                                               \
            _Pragma("unroll")                                                  \
            for (int mf = 0; mf < 4; ++mf)                                     \
                af[mf] = *(const short8*)&As[(wr * 64 + mf * 16 + lr) * 64 + kk * 32 + lk]; \
            _Pragma("unroll")                                                  \
            for (int nf = 0; nf < 4; ++nf)                                     \
                bf[nf] = *(const short8*)&Bs[(wc * 64 + nf * 16 + lr) * 64 + kk * 32 + lk]; \
            _Pragma("unroll")                                                  \
            for (int mf = 0; mf < 4; ++mf)                                     \
                _Pragma("unroll")                                              \
                for (int nf = 0; nf < 4; ++nf)                                 \
                    acc[mf][nf] = __builtin_amdgcn_mfma_f32_16x16x32_bf16(     \
                        af[mf], bf[nf], acc[mf][nf], 0, 0, 0);                 \
        }                                                                      \
    }

// ---------------------------------------------------------------------------
// k1_97: tableA[p][m][j] = sum_i bb[m][i] * posT[p][j][i]  (bf16 out)
// Grid (4 j-tiles, 2 m-tiles, 16 p).
// ---------------------------------------------------------------------------
__global__ __launch_bounds__(256) void k1_97(
    const unsigned short* __restrict__ A,   // bb [256][512]
    const unsigned short* __restrict__ PT,  // posT [16][512][512] ([p][j][i])
    unsigned short* __restrict__ T)         // tableA [16][257][512]
{
    const int p  = blockIdx.z;
    const int n0 = blockIdx.x * 128;   // j
    const int m0 = blockIdx.y * 128;   // m
    const unsigned short* __restrict__ Ag = A + (size_t)m0 * 512;
    const unsigned short* __restrict__ Bg = PT + (size_t)p * 512 * 512 + (size_t)n0 * 512;
    unsigned short* __restrict__ Tp = T + (size_t)p * TA_P_STRIDE;

    GEMM_PROLOG();
    GEMM_MAIN();

    #pragma unroll
    for (int nf = 0; nf < 4; ++nf)
        #pragma unroll
        for (int mf = 0; mf < 4; ++mf)
            #pragma unroll
            for (int q = 0; q < 4; ++q)
                Tp[(size_t)(m0 + wr * 64 + mf * 16 + lg * 4 + q) * 512
                   + n0 + wc * 64 + nf * 16 + lr]
                    = (unsigned short)f2bfu(acc[mf][nf][q]);
}

// ---------------------------------------------------------------------------
// k_up97: out[m][d] = sum_j e_pre[m][j]*wb[d][j] + up_b[d]   (fp32 out)
// Grid (8 d-tiles, 64 m-tiles).
// ---------------------------------------------------------------------------
__global__ __launch_bounds__(256) void k_up97(
    const unsigned short* __restrict__ Aep,  // e_pre [8192][512]
    const unsigned short* __restrict__ Wb,   // up_w  [1024][512]
    const float* __restrict__ up_b,
    float* __restrict__ out)                 // [8192][1024]
{
    const int n0 = blockIdx.x * 128;
    const int m0 = blockIdx.y * 128;
    const unsigned short* __restrict__ Ag = Aep + (size_t)m0 * 512;
    const unsigned short* __restrict__ Bg = Wb + (size_t)n0 * 512;

    GEMM_PROLOG();
    GEMM_MAIN();

    #pragma unroll
    for (int nf = 0; nf < 4; ++nf) {
        const int col = n0 + wc * 64 + nf * 16 + lr;
        const float bias = up_b[col];
        #pragma unroll
        for (int mf = 0; mf < 4; ++mf)
            #pragma unroll
            for (int q = 0; q < 4; ++q)
                out[(size_t)(m0 + wr * 64 + mf * 16 + lg * 4 + q) * 1024 + col]
                    = acc[mf][nf][q] + bias;
    }
}

// ---------------------------------------------------------------------------
// k_gather: e_pre[row][j] = sum_p tableA[p][idr(row,p)][j]  (fp32 accum, bf16
// out). One wave per row, 4 rows/block. Branchless via pad row.
// ---------------------------------------------------------------------------
__global__ __launch_bounds__(256) void k_gather(
    const int* __restrict__ ids,
    const unsigned short* __restrict__ T,
    unsigned short* __restrict__ e_pre)
{
    const int row  = blockIdx.x * 4 + (threadIdx.x >> 6);
    const int lane = threadIdx.x & 63;
    const int* __restrict__ idr = ids + row * 16;

    float acc[8] = {};
    #pragma unroll
    for (int p = 0; p < 16; ++p) {
        const int id = idr[p];
        const unsigned int off = (unsigned int)((p * 257 + (id < 0 ? 256 : id)) * 512);
        const short8 v = *(const short8*)&T[off + lane * 8];
        #pragma unroll
        for (int j = 0; j < 8; ++j)
            acc[j] += bf2f((unsigned short)v[j]);
    }
    short8 r;
    #pragma unroll
    for (int j = 0; j < 8; ++j) r[j] = (short)f2bfu(acc[j]);
    *(short8*)&e_pre[(size_t)row * 512 + lane * 8] = r;
}

// ---------------------------------------------------------------------------
// k_ln: in-place LayerNorm over out rows of 1024. Block per row, 256 thr.
// ---------------------------------------------------------------------------
__global__ __launch_bounds__(256) void k_ln(
    const float* __restrict__ gamma,
    const float* __restrict__ beta,
    float* __restrict__ out)
{
    const int row = blockIdx.x;
    const int tid = threadIdx.x;

    float4 acc = *(const float4*)&out[(size_t)row * 1024 + tid * 4];

    float s  = acc.x + acc.y + acc.z + acc.w;
    float ss = acc.x * acc.x + acc.y * acc.y + acc.z * acc.z + acc.w * acc.w;
    #pragma unroll
    for (int off = 32; off > 0; off >>= 1) {
        s  += __shfl_down(s,  off, 64);
        ss += __shfl_down(ss, off, 64);
    }

    __shared__ float red[8];
    const int wid = tid >> 6, lane = tid & 63;
    if (lane == 0) { red[wid] = s; red[4 + wid] = ss; }
    __syncthreads();

    const float S   = red[0] + red[1] + red[2] + red[3];
    const float SS  = red[4] + red[5] + red[6] + red[7];
    const float mu  = S * (1.0f / 1024.0f);
    const float var = SS * (1.0f / 1024.0f) - mu * mu;
    const float rstd = rsqrtf(var + LN_EPS);

    const float4 g = *(const float4*)&gamma[tid * 4];
    const float4 b = *(const float4*)&beta[tid * 4];
    float4 o;
    o.x = (acc.x - mu) * rstd * g.x + b.x;
    o.y = (acc.y - mu) * rstd * g.y + b.y;
    o.z = (acc.z - mu) * rstd * g.z + b.z;
    o.w = (acc.w - mu) * rstd * g.w + b.w;
    *(float4*)&out[(size_t)row * 1024 + tid * 4] = o;
}

extern "C" void kernel_launch(void* const* d_in, const int* in_sizes, int n_in,
                              void* d_out, int out_size, void* d_ws, size_t ws_size,
                              hipStream_t stream) {
    const int*   ids      = (const int*)d_in[0];
    const float* byte_emb = (const float*)d_in[1];
    const float* pos_emb  = (const float*)d_in[2];
    const float* up_w     = (const float*)d_in[3];
    const float* up_b     = (const float*)d_in[4];
    const float* gamma    = (const float*)d_in[5];
    const float* beta     = (const float*)d_in[6];
    float* out = (float*)d_out;

    // ws: wb 1MB | bb 0.25MB | posT 8MB | tableA ~4.2MB | e_pre 8MB
    unsigned short* wb     = (unsigned short*)d_ws;
    unsigned short* bb     = wb + (size_t)1024 * 512;
    unsigned short* posT   = bb + (size_t)256 * 512;
    unsigned short* tableA = posT + (size_t)16 * 512 * 512;
    unsigned short* e_pre  = tableA + (size_t)16 * TA_P_STRIDE;

    const int rows = in_sizes[0] / 16;   // 8192

    k_prep<<<1680, 256, 0, stream>>>(up_w, byte_emb, pos_emb, wb, bb, tableA, posT);

    dim3 g1(4, 2, 16);
    k1_97<<<g1, 256, 0, stream>>>(bb, posT, tableA);

    k_gather<<<rows / 4, 256, 0, stream>>>(ids, tableA, e_pre);

    dim3 g2(8, 64);
    k_up97<<<g2, 256, 0, stream>>>(e_pre, wb, up_b, out);

    k_ln<<<rows, 256, 0, stream>>>(gamma, beta, out);
}

// Round 10
// 104.450 us; speedup vs baseline: 1.2806x; 1.0115x over previous
//
#include <hip/hip_runtime.h>
#include <hip/hip_bf16.h>

#define LN_EPS 1e-5f

typedef __attribute__((ext_vector_type(8))) short short8;
typedef __attribute__((ext_vector_type(4))) float floatx4;

static __device__ __forceinline__ unsigned int f2bfu(float f) {
    __hip_bfloat16 h = __float2bfloat16(f);
    return (unsigned int)__builtin_bit_cast(unsigned short, h);
}
static __device__ __forceinline__ float bf2f(unsigned short u) {
    return __builtin_bit_cast(float, (unsigned int)u << 16);
}

#define TA_P_STRIDE (257 * 512)   // tableA: [16][257][512] bf16; row 256 = zeros

// ---------------------------------------------------------------------------
// k_prep: blocks 0..511 cast up_w -> wb; 512..639 cast byte_emb -> bb;
// 640..655 zero tableA pad rows; 656..1679 transpose-cast pos_emb -> posT.
// ---------------------------------------------------------------------------
__global__ __launch_bounds__(256) void k_prep(
    const float* __restrict__ up_w, const float* __restrict__ byte_emb,
    const float* __restrict__ pos_emb,
    unsigned short* __restrict__ wb, unsigned short* __restrict__ bb,
    unsigned short* __restrict__ T, unsigned short* __restrict__ PT)
{
    const int b = blockIdx.x;
    if (b < 640) {
        const float* src;
        unsigned short* dst;
        int idx;
        if (b < 512) { src = up_w;     dst = wb; idx = (b * 256 + threadIdx.x) * 4; }
        else         { src = byte_emb; dst = bb; idx = ((b - 512) * 256 + threadIdx.x) * 4; }
        const float4 v = *(const float4*)&src[idx];
        ushort4 o;
        o.x = (unsigned short)f2bfu(v.x); o.y = (unsigned short)f2bfu(v.y);
        o.z = (unsigned short)f2bfu(v.z); o.w = (unsigned short)f2bfu(v.w);
        *(ushort4*)&dst[idx] = o;
    } else if (b < 656) {
        const int p = b - 640;
        if (threadIdx.x < 128) {
            ushort4 z; z.x = z.y = z.z = z.w = 0;
            *(ushort4*)&T[(size_t)p * TA_P_STRIDE + 256 * 512 + threadIdx.x * 4] = z;
        }
    } else {
        // transpose-cast: pos_emb [p][i][j] f32 -> posT [p][j][i] bf16
        const int idx = b - 656;
        const int j0 = (idx & 7) * 64;
        const int i0 = ((idx >> 3) & 7) * 64;
        const int p  = idx >> 6;
        const float* __restrict__ Pp = pos_emb + (size_t)p * 512 * 512;
        unsigned short* __restrict__ Tp = PT + (size_t)p * 512 * 512;

        __shared__ float S[64][65];
        const int r  = threadIdx.x >> 2;
        const int c0 = (threadIdx.x & 3) * 16;

        #pragma unroll
        for (int c = 0; c < 16; c += 4) {
            const float4 v = *(const float4*)&Pp[(size_t)(i0 + r) * 512 + j0 + c0 + c];
            S[r][c0 + c + 0] = v.x;
            S[r][c0 + c + 1] = v.y;
            S[r][c0 + c + 2] = v.z;
            S[r][c0 + c + 3] = v.w;
        }
        __syncthreads();

        #pragma unroll
        for (int h = 0; h < 2; ++h) {
            short8 o;
            #pragma unroll
            for (int k = 0; k < 8; ++k)
                o[k] = (short)f2bfu(S[c0 + h * 8 + k][r]);
            *(short8*)&Tp[(size_t)(j0 + r) * 512 + i0 + c0 + h * 8] = o;
        }
    }
}

// ---------------------------------------------------------------------------
// Shared m97-style GEMM body. Block 256 thr = 4 waves (2x2), BM=BN=128, BK=64,
// both operands K-major, row stride 512. Coalesced reg-staging -> linear LDS,
// ds_read_b128 frags, 2 barriers/iter, T14 early loads.
// Epilogue: acc staged through LDS (Cst, aliased onto As/Bs) in 32-row
// quarters, then written as full contiguous rows (one store per L2 line).
// ---------------------------------------------------------------------------
#define GEMM_PROLOG()                                                          \
    __shared__ __align__(16) unsigned short SMEM[2 * 128 * 64];                \
    unsigned short* As = SMEM;                                                 \
    unsigned short* Bs = SMEM + 128 * 64;                                      \
    float (*Cst)[132] = (float(*)[132])SMEM;                                   \
    const int tid = threadIdx.x;                                               \
    const int w   = tid >> 6, lane = tid & 63;                                 \
    const int lr  = lane & 15, lg = lane >> 4, lk = lg * 8;                    \
    const int wr  = w >> 1, wc = w & 1;                                        \
    const int srow = tid >> 3, schunk = (tid & 7) * 8;                         \
    uint4 ra[4], rb[4];                                                        \
    floatx4 acc[4][4] = {};

#define GEMM_LOAD(kt)                                                          \
    _Pragma("unroll")                                                          \
    for (int i = 0; i < 4; ++i) {                                              \
        ra[i] = *(const uint4*)&Ag[(size_t)(i * 32 + srow) * 512 + (kt) * 64 + schunk]; \
        rb[i] = *(const uint4*)&Bg[(size_t)(i * 32 + srow) * 512 + (kt) * 64 + schunk]; \
    }

#define GEMM_STORE()                                                           \
    _Pragma("unroll")                                                          \
    for (int i = 0; i < 4; ++i) {                                              \
        *(uint4*)&As[(i * 32 + srow) * 64 + schunk] = ra[i];                   \
        *(uint4*)&Bs[(i * 32 + srow) * 64 + schunk] = rb[i];                   \
    }

#define GEMM_MAIN()                                                            \
    GEMM_LOAD(0);                                                              \
    for (int kt = 0; kt < 8; ++kt) {                                           \
        __syncthreads();                                                       \
        GEMM_STORE();                                                          \
        __syncthreads();                                                       \
        if (kt < 7) { GEMM_LOAD(kt + 1); }                                     \
        _Pragma("unroll")                                                      \
        for (int kk = 0; kk < 2; ++kk) {                                       \
            short8 af[4], bf[4];                                               \
            _Pragma("unroll")                                                  \
            for (int mf = 0; mf < 4; ++mf)                                     \
                af[mf] = *(const short8*)&As[(wr * 64 + mf * 16 + lr) * 64 + kk * 32 + lk]; \
            _Pragma("unroll")                                                  \
            for (int nf = 0; nf < 4; ++nf)                                     \
                bf[nf] = *(const short8*)&Bs[(wc * 64 + nf * 16 + lr) * 64 + kk * 32 + lk]; \
            _Pragma("unroll")                                                  \
            for (int mf = 0; mf < 4; ++mf)                                     \
                _Pragma("unroll")                                              \
                for (int nf = 0; nf < 4; ++nf)                                 \
                    acc[mf][nf] = __builtin_amdgcn_mfma_f32_16x16x32_bf16(     \
                        af[mf], bf[nf], acc[mf][nf], 0, 0, 0);                 \
        }                                                                      \
    }                                                                          \
    __syncthreads();   /* all LDS frag reads done; safe to alias Cst */

// Stage one 32-row quarter of acc (+per-col add 'addv') into Cst.
#define CST_STAGE(qr, addv)                                                    \
    if (wr == ((qr) >> 1)) {                                                   \
        _Pragma("unroll")                                                      \
        for (int mfq = 0; mfq < 2; ++mfq) {                                    \
            const int mf = ((qr) & 1) * 2 + mfq;                               \
            _Pragma("unroll")                                                  \
            for (int nf = 0; nf < 4; ++nf)                                     \
                _Pragma("unroll")                                              \
                for (int q = 0; q < 4; ++q)                                    \
                    Cst[mfq * 16 + lg * 4 + q][wc * 64 + nf * 16 + lr]         \
                        = acc[mf][nf][q] + addv;                               \
        }                                                                      \
    }

// ---------------------------------------------------------------------------
// k1_97: tableA[p][m][j] = sum_i bb[m][i] * posT[p][j][i]  (bf16 out)
// Grid (4 j-tiles, 2 m-tiles, 16 p) = 128 blocks.
// ---------------------------------------------------------------------------
__global__ __launch_bounds__(256) void k1_97(
    const unsigned short* __restrict__ A,   // bb [256][512]
    const unsigned short* __restrict__ PT,  // posT [16][512][512] ([p][j][i])
    unsigned short* __restrict__ T)         // tableA [16][257][512]
{
    const int p  = blockIdx.z;
    const int n0 = blockIdx.x * 128;   // j
    const int m0 = blockIdx.y * 128;   // m
    const unsigned short* __restrict__ Ag = A + (size_t)m0 * 512;
    const unsigned short* __restrict__ Bg = PT + (size_t)p * 512 * 512 + (size_t)n0 * 512;
    unsigned short* __restrict__ Tp = T + (size_t)p * TA_P_STRIDE;

    GEMM_PROLOG();
    GEMM_MAIN();

    #pragma unroll
    for (int qr = 0; qr < 4; ++qr) {
        CST_STAGE(qr, 0.0f);
        __syncthreads();
        #pragma unroll
        for (int pass = 0; pass < 2; ++pass) {
            const int row = pass * 16 + (tid >> 4);
            const int c8  = (tid & 15) * 8;
            uint4 o;
            o.x = f2bfu(Cst[row][c8 + 0]) | (f2bfu(Cst[row][c8 + 1]) << 16);
            o.y = f2bfu(Cst[row][c8 + 2]) | (f2bfu(Cst[row][c8 + 3]) << 16);
            o.z = f2bfu(Cst[row][c8 + 4]) | (f2bfu(Cst[row][c8 + 5]) << 16);
            o.w = f2bfu(Cst[row][c8 + 6]) | (f2bfu(Cst[row][c8 + 7]) << 16);
            *(uint4*)&Tp[(size_t)(m0 + qr * 32 + row) * 512 + n0 + c8] = o;
        }
        __syncthreads();
    }
}

// ---------------------------------------------------------------------------
// k_up97: out[m][d] = sum_j e_pre[m][j]*wb[d][j] + up_b[d]   (fp32 out)
// Grid (8 d-tiles, 64 m-tiles) = 512 blocks, XCD-swizzled (T1).
// ---------------------------------------------------------------------------
__global__ __launch_bounds__(256) void k_up97(
    const unsigned short* __restrict__ Aep,  // e_pre [8192][512]
    const unsigned short* __restrict__ Wb,   // up_w  [1024][512]
    const float* __restrict__ up_b,
    float* __restrict__ out)                 // [8192][1024]
{
    // XCD swizzle: nwg=512, 8 XCDs. XCD x gets m-tiles 8x..8x+7, all n-tiles.
    const int bid = blockIdx.y * 8 + blockIdx.x;
    const int swz = (bid & 7) * 64 + (bid >> 3);
    const int n0 = (swz & 7) * 128;
    const int m0 = (swz >> 3) * 128;
    const unsigned short* __restrict__ Ag = Aep + (size_t)m0 * 512;
    const unsigned short* __restrict__ Bg = Wb + (size_t)n0 * 512;

    GEMM_PROLOG();
    GEMM_MAIN();

    float biasv[4];
    #pragma unroll
    for (int nf = 0; nf < 4; ++nf) biasv[nf] = up_b[n0 + wc * 64 + nf * 16 + lr];

    #pragma unroll
    for (int qr = 0; qr < 4; ++qr) {
        CST_STAGE(qr, biasv[nf]);
        __syncthreads();
        #pragma unroll
        for (int pass = 0; pass < 4; ++pass) {
            const int row = pass * 8 + (tid >> 5);
            const int c4  = (tid & 31) * 4;
            const float4 v = make_float4(Cst[row][c4 + 0], Cst[row][c4 + 1],
                                         Cst[row][c4 + 2], Cst[row][c4 + 3]);
            *(float4*)&out[(size_t)(m0 + qr * 32 + row) * 1024 + n0 + c4] = v;
        }
        __syncthreads();
    }
}

// ---------------------------------------------------------------------------
// k_gather: e_pre[row][j] = sum_p tableA[p][idr(row,p)][j]  (fp32 accum, bf16
// out). One wave per row, 4 rows/block. Branchless via pad row.
// ---------------------------------------------------------------------------
__global__ __launch_bounds__(256) void k_gather(
    const int* __restrict__ ids,
    const unsigned short* __restrict__ T,
    unsigned short* __restrict__ e_pre)
{
    const int row  = blockIdx.x * 4 + (threadIdx.x >> 6);
    const int lane = threadIdx.x & 63;
    const int* __restrict__ idr = ids + row * 16;

    float acc[8] = {};
    #pragma unroll
    for (int p = 0; p < 16; ++p) {
        const int id = idr[p];
        const unsigned int off = (unsigned int)((p * 257 + (id < 0 ? 256 : id)) * 512);
        const short8 v = *(const short8*)&T[off + lane * 8];
        #pragma unroll
        for (int j = 0; j < 8; ++j)
            acc[j] += bf2f((unsigned short)v[j]);
    }
    short8 r;
    #pragma unroll
    for (int j = 0; j < 8; ++j) r[j] = (short)f2bfu(acc[j]);
    *(short8*)&e_pre[(size_t)row * 512 + lane * 8] = r;
}

// ---------------------------------------------------------------------------
// k_ln: in-place LayerNorm over out rows of 1024. Block per row, 256 thr.
// ---------------------------------------------------------------------------
__global__ __launch_bounds__(256) void k_ln(
    const float* __restrict__ gamma,
    const float* __restrict__ beta,
    float* __restrict__ out)
{
    const int row = blockIdx.x;
    const int tid = threadIdx.x;

    float4 acc = *(const float4*)&out[(size_t)row * 1024 + tid * 4];

    float s  = acc.x + acc.y + acc.z + acc.w;
    float ss = acc.x * acc.x + acc.y * acc.y + acc.z * acc.z + acc.w * acc.w;
    #pragma unroll
    for (int off = 32; off > 0; off >>= 1) {
        s  += __shfl_down(s,  off, 64);
        ss += __shfl_down(ss, off, 64);
    }

    __shared__ float red[8];
    const int wid = tid >> 6, lane = tid & 63;
    if (lane == 0) { red[wid] = s; red[4 + wid] = ss; }
    __syncthreads();

    const float S   = red[0] + red[1] + red[2] + red[3];
    const float SS  = red[4] + red[5] + red[6] + red[7];
    const float mu  = S * (1.0f / 1024.0f);
    const float var = SS * (1.0f / 1024.0f) - mu * mu;
    const float rstd = rsqrtf(var + LN_EPS);

    const float4 g = *(const float4*)&gamma[tid * 4];
    const float4 b = *(const float4*)&beta[tid * 4];
    float4 o;
    o.x = (acc.x - mu) * rstd * g.x + b.x;
    o.y = (acc.y - mu) * rstd * g.y + b.y;
    o.z = (acc.z - mu) * rstd * g.z + b.z;
    o.w = (acc.w - mu) * rstd * g.w + b.w;
    *(float4*)&out[(size_t)row * 1024 + tid * 4] = o;
}

extern "C" void kernel_launch(void* const* d_in, const int* in_sizes, int n_in,
                              void* d_out, int out_size, void* d_ws, size_t ws_size,
                              hipStream_t stream) {
    const int*   ids      = (const int*)d_in[0];
    const float* byte_emb = (const float*)d_in[1];
    const float* pos_emb  = (const float*)d_in[2];
    const float* up_w     = (const float*)d_in[3];
    const float* up_b     = (const float*)d_in[4];
    const float* gamma    = (const float*)d_in[5];
    const float* beta     = (const float*)d_in[6];
    float* out = (float*)d_out;

    // ws: wb 1MB | bb 0.25MB | posT 8MB | tableA ~4.2MB | e_pre 8MB
    unsigned short* wb     = (unsigned short*)d_ws;
    unsigned short* bb     = wb + (size_t)1024 * 512;
    unsigned short* posT   = bb + (size_t)256 * 512;
    unsigned short* tableA = posT + (size_t)16 * 512 * 512;
    unsigned short* e_pre  = tableA + (size_t)16 * TA_P_STRIDE;

    const int rows = in_sizes[0] / 16;   // 8192

    k_prep<<<1680, 256, 0, stream>>>(up_w, byte_emb, pos_emb, wb, bb, tableA, posT);

    dim3 g1(4, 2, 16);
    k1_97<<<g1, 256, 0, stream>>>(bb, posT, tableA);

    k_gather<<<rows / 4, 256, 0, stream>>>(ids, tableA, e_pre);

    dim3 g2(8, 64);
    k_up97<<<g2, 256, 0, stream>>>(e_pre, wb, up_b, out);

    k_ln<<<rows, 256, 0, stream>>>(gamma, beta, out);
}

// Round 12
// 58.714 us; speedup vs baseline: 2.2782x; 1.7790x over previous
//
#include <hip/hip_runtime.h>
#include <hip/hip_bf16.h>

#define LN_EPS 1e-5f

typedef __attribute__((ext_vector_type(8))) short short8;
typedef __attribute__((ext_vector_type(4))) float floatx4;

static __device__ __forceinline__ unsigned int f2bfu(float f) {
    __hip_bfloat16 h = __float2bfloat16(f);
    return (unsigned int)__builtin_bit_cast(unsigned short, h);
}
static __device__ __forceinline__ float bf2f(unsigned short u) {
    return __builtin_bit_cast(float, (unsigned int)u << 16);
}

// async global->LDS, 16B per lane: LDS dest = wave-uniform base + lane*16,
// global src = per-lane address (m03/m97/m104 semantics).
static __device__ __forceinline__ void gload_lds16(const void* g, void* l) {
    __builtin_amdgcn_global_load_lds(
        (const __attribute__((address_space(1))) void*)g,
        (__attribute__((address_space(3))) void*)l, 16, 0, 0);
}

#define TA_P_STRIDE (257 * 512)   // tableA: [16][257][512] bf16; row 256 = zeros

// ---------------------------------------------------------------------------
// k_prep: blocks 0..511 cast up_w -> wb; 512..639 cast byte_emb -> bb;
// 640..655 zero tableA pad rows; 656..1679 transpose-cast pos_emb -> posT.
// ---------------------------------------------------------------------------
__global__ __launch_bounds__(256) void k_prep(
    const float* __restrict__ up_w, const float* __restrict__ byte_emb,
    const float* __restrict__ pos_emb,
    unsigned short* __restrict__ wb, unsigned short* __restrict__ bb,
    unsigned short* __restrict__ T, unsigned short* __restrict__ PT)
{
    const int b = blockIdx.x;
    if (b < 640) {
        const float* src;
        unsigned short* dst;
        int idx;
        if (b < 512) { src = up_w;     dst = wb; idx = (b * 256 + threadIdx.x) * 4; }
        else         { src = byte_emb; dst = bb; idx = ((b - 512) * 256 + threadIdx.x) * 4; }
        const float4 v = *(const float4*)&src[idx];
        ushort4 o;
        o.x = (unsigned short)f2bfu(v.x); o.y = (unsigned short)f2bfu(v.y);
        o.z = (unsigned short)f2bfu(v.z); o.w = (unsigned short)f2bfu(v.w);
        *(ushort4*)&dst[idx] = o;
    } else if (b < 656) {
        const int p = b - 640;
        if (threadIdx.x < 128) {
            ushort4 z; z.x = z.y = z.z = z.w = 0;
            *(ushort4*)&T[(size_t)p * TA_P_STRIDE + 256 * 512 + threadIdx.x * 4] = z;
        }
    } else {
        // transpose-cast: pos_emb [p][i][j] f32 -> posT [p][j][i] bf16
        const int idx = b - 656;
        const int j0 = (idx & 7) * 64;
        const int i0 = ((idx >> 3) & 7) * 64;
        const int p  = idx >> 6;
        const float* __restrict__ Pp = pos_emb + (size_t)p * 512 * 512;
        unsigned short* __restrict__ Tp = PT + (size_t)p * 512 * 512;

        __shared__ float S[64][65];
        const int r  = threadIdx.x >> 2;
        const int c0 = (threadIdx.x & 3) * 16;

        #pragma unroll
        for (int c = 0; c < 16; c += 4) {
            const float4 v = *(const float4*)&Pp[(size_t)(i0 + r) * 512 + j0 + c0 + c];
            S[r][c0 + c + 0] = v.x;
            S[r][c0 + c + 1] = v.y;
            S[r][c0 + c + 2] = v.z;
            S[r][c0 + c + 3] = v.w;
        }
        __syncthreads();

        #pragma unroll
        for (int h = 0; h < 2; ++h) {
            short8 o;
            #pragma unroll
            for (int k = 0; k < 8; ++k)
                o[k] = (short)f2bfu(S[c0 + h * 8 + k][r]);
            *(short8*)&Tp[(size_t)(j0 + r) * 512 + i0 + c0 + h * 8] = o;
        }
    }
}

// ---------------------------------------------------------------------------
// gload_lds 2-phase GEMM template. Block 256 thr = 4 waves (2x2), BM=BN=128,
// BK=64, operands K-major (row stride 512). LDS: 2 buffers x (A 16KB + B 16KB)
// = 64KB, LINEAR layout (row*128B + kcol*2B). Per iter: STAGE(next buf) via
// 8 global_load_lds per wave, COMPUTE(cur buf), ONE __syncthreads (its
// implicit vmcnt(0) drain is exactly the wait for the staged loads).
// Epilogue: Cst LDS staging -> full-row coalesced stores.
// ---------------------------------------------------------------------------
#define GEMM_PROLOG()                                                          \
    __shared__ __align__(16) unsigned short SMEM[32768]; /* 64 KB */           \
    float (*Cst)[132] = (float(*)[132])SMEM;                                   \
    const int tid = threadIdx.x;                                               \
    const int w   = tid >> 6, lane = tid & 63;                                 \
    const int lr  = lane & 15, lg = lane >> 4, lk = lg * 8;                    \
    const int wr  = w >> 1, wc = w & 1;                                        \
    const int crow = lane >> 3, ccol = (lane & 7) * 8;                         \
    floatx4 acc[4][4] = {};

// stage tile kt into buffer b (A rows/B rows: chunk c = 8 rows x 64 cols)
#define GEMM_STAGE(b, kt) do {                                                 \
    unsigned short* Ab = SMEM + (b) * 16384;                                   \
    unsigned short* Bb = Ab + 8192;                                            \
    _Pragma("unroll")                                                          \
    for (int ci = 0; ci < 4; ++ci) {                                           \
        const int c = w + ci * 4;                                              \
        gload_lds16(&Ag[(size_t)(c * 8 + crow) * 512 + (kt) * 64 + ccol],      \
                    &Ab[c * 512]);                                             \
        gload_lds16(&Bg[(size_t)(c * 8 + crow) * 512 + (kt) * 64 + ccol],      \
                    &Bb[c * 512]);                                             \
    }                                                                          \
} while (0)

#define GEMM_COMPUTE(b) do {                                                   \
    const unsigned short* As = SMEM + (b) * 16384;                             \
    const unsigned short* Bs = As + 8192;                                      \
    _Pragma("unroll")                                                          \
    for (int kk = 0; kk < 2; ++kk) {                                           \
        short8 af[4], bf[4];                                                   \
        _Pragma("unroll")                                                      \
        for (int mf = 0; mf < 4; ++mf)                                         \
            af[mf] = *(const short8*)&As[(wr * 64 + mf * 16 + lr) * 64 + kk * 32 + lk]; \
        _Pragma("unroll")                                                      \
        for (int nf = 0; nf < 4; ++nf)                                         \
            bf[nf] = *(const short8*)&Bs[(wc * 64 + nf * 16 + lr) * 64 + kk * 32 + lk]; \
        _Pragma("unroll")                                                      \
        for (int mf = 0; mf < 4; ++mf)                                         \
            _Pragma("unroll")                                                  \
            for (int nf = 0; nf < 4; ++nf)                                     \
                acc[mf][nf] = __builtin_amdgcn_mfma_f32_16x16x32_bf16(         \
                    af[mf], bf[nf], acc[mf][nf], 0, 0, 0);                     \
    }                                                                          \
} while (0)

#define GEMM_MAIN()                                                            \
    GEMM_STAGE(0, 0);                                                          \
    __syncthreads();                                                           \
    {                                                                          \
        int buf = 0;                                                           \
        for (int kt = 0; kt < 8; ++kt) {                                       \
            if (kt < 7) GEMM_STAGE(buf ^ 1, kt + 1);                           \
            GEMM_COMPUTE(buf);                                                 \
            __syncthreads();                                                   \
            buf ^= 1;                                                          \
        }                                                                      \
    }

// Stage one 32-row quarter of acc (+per-col add 'addv') into Cst.
#define CST_STAGE(qr, addv)                                                    \
    if (wr == ((qr) >> 1)) {                                                   \
        _Pragma("unroll")                                                      \
        for (int mfq = 0; mfq < 2; ++mfq) {                                    \
            const int mf = ((qr) & 1) * 2 + mfq;                               \
            _Pragma("unroll")                                                  \
            for (int nf = 0; nf < 4; ++nf)                                     \
                _Pragma("unroll")                                              \
                for (int q = 0; q < 4; ++q)                                    \
                    Cst[mfq * 16 + lg * 4 + q][wc * 64 + nf * 16 + lr]         \
                        = acc[mf][nf][q] + addv;                               \
        }                                                                      \
    }

// ---------------------------------------------------------------------------
// k1_97: tableA[p][m][j] = sum_i bb[m][i] * posT[p][j][i]  (bf16 out)
// Grid (4 j-tiles, 2 m-tiles, 16 p) = 128 blocks.
// ---------------------------------------------------------------------------
__global__ __launch_bounds__(256) void k1_97(
    const unsigned short* __restrict__ A,   // bb [256][512]
    const unsigned short* __restrict__ PT,  // posT [16][512][512] ([p][j][i])
    unsigned short* __restrict__ T)         // tableA [16][257][512]
{
    const int p  = blockIdx.z;
    const int n0 = blockIdx.x * 128;   // j
    const int m0 = blockIdx.y * 128;   // m
    const unsigned short* __restrict__ Ag = A + (size_t)m0 * 512;
    const unsigned short* __restrict__ Bg = PT + (size_t)p * 512 * 512 + (size_t)n0 * 512;
    unsigned short* __restrict__ Tp = T + (size_t)p * TA_P_STRIDE;

    GEMM_PROLOG();
    GEMM_MAIN();
    __syncthreads();   // all LDS frag reads done; safe to alias Cst

    #pragma unroll
    for (int qr = 0; qr < 4; ++qr) {
        CST_STAGE(qr, 0.0f);
        __syncthreads();
        #pragma unroll
        for (int pass = 0; pass < 2; ++pass) {
            const int row = pass * 16 + (tid >> 4);
            const int c8  = (tid & 15) * 8;
            uint4 o;
            o.x = f2bfu(Cst[row][c8 + 0]) | (f2bfu(Cst[row][c8 + 1]) << 16);
            o.y = f2bfu(Cst[row][c8 + 2]) | (f2bfu(Cst[row][c8 + 3]) << 16);
            o.z = f2bfu(Cst[row][c8 + 4]) | (f2bfu(Cst[row][c8 + 5]) << 16);
            o.w = f2bfu(Cst[row][c8 + 6]) | (f2bfu(Cst[row][c8 + 7]) << 16);
            *(uint4*)&Tp[(size_t)(m0 + qr * 32 + row) * 512 + n0 + c8] = o;
        }
        __syncthreads();
    }
}

// ---------------------------------------------------------------------------
// k_up97: out[m][d] = sum_j e_pre[m][j]*wb[d][j] + up_b[d]   (fp32 out, NT)
// Grid (8 d-tiles, 64 m-tiles) = 512 blocks, XCD-swizzled (T1).
// ---------------------------------------------------------------------------
__global__ __launch_bounds__(256) void k_up97(
    const unsigned short* __restrict__ Aep,  // e_pre [8192][512]
    const unsigned short* __restrict__ Wb,   // up_w  [1024][512]
    const float* __restrict__ up_b,
    float* __restrict__ out)                 // [8192][1024]
{
    // XCD swizzle: nwg=512, 8 XCDs. XCD x gets m-tiles 8x..8x+7, all n-tiles.
    const int bid = blockIdx.y * 8 + blockIdx.x;
    const int swz = (bid & 7) * 64 + (bid >> 3);
    const int n0 = (swz & 7) * 128;
    const int m0 = (swz >> 3) * 128;
    const unsigned short* __restrict__ Ag = Aep + (size_t)m0 * 512;
    const unsigned short* __restrict__ Bg = Wb + (size_t)n0 * 512;

    GEMM_PROLOG();
    GEMM_MAIN();
    __syncthreads();   // all LDS frag reads done; safe to alias Cst

    float biasv[4];
    #pragma unroll
    for (int nf = 0; nf < 4; ++nf) biasv[nf] = up_b[n0 + wc * 64 + nf * 16 + lr];

    #pragma unroll
    for (int qr = 0; qr < 4; ++qr) {
        CST_STAGE(qr, biasv[nf]);
        __syncthreads();
        #pragma unroll
        for (int pass = 0; pass < 4; ++pass) {
            const int row = pass * 8 + (tid >> 5);
            const int c4  = (tid & 31) * 4;
            floatx4 v;
            v[0] = Cst[row][c4 + 0]; v[1] = Cst[row][c4 + 1];
            v[2] = Cst[row][c4 + 2]; v[3] = Cst[row][c4 + 3];
            __builtin_nontemporal_store(
                v, (floatx4*)&out[(size_t)(m0 + qr * 32 + row) * 1024 + n0 + c4]);
        }
        __syncthreads();
    }
}

// ---------------------------------------------------------------------------
// k_gather: e_pre[row][j] = sum_p tableA[p][idr(row,p)][j]  (fp32 accum, bf16
// out). One wave per row, 4 rows/block. Branchless via pad row.
// ---------------------------------------------------------------------------
__global__ __launch_bounds__(256) void k_gather(
    const int* __restrict__ ids,
    const unsigned short* __restrict__ T,
    unsigned short* __restrict__ e_pre)
{
    const int row  = blockIdx.x * 4 + (threadIdx.x >> 6);
    const int lane = threadIdx.x & 63;
    const int* __restrict__ idr = ids + row * 16;

    float acc[8] = {};
    #pragma unroll
    for (int p = 0; p < 16; ++p) {
        const int id = idr[p];
        const unsigned int off = (unsigned int)((p * 257 + (id < 0 ? 256 : id)) * 512);
        const short8 v = *(const short8*)&T[off + lane * 8];
        #pragma unroll
        for (int j = 0; j < 8; ++j)
            acc[j] += bf2f((unsigned short)v[j]);
    }
    short8 r;
    #pragma unroll
    for (int j = 0; j < 8; ++j) r[j] = (short)f2bfu(acc[j]);
    *(short8*)&e_pre[(size_t)row * 512 + lane * 8] = r;
}

// ---------------------------------------------------------------------------
// k_ln: in-place LayerNorm over out rows of 1024. Block per row, 256 thr.
// ---------------------------------------------------------------------------
__global__ __launch_bounds__(256) void k_ln(
    const float* __restrict__ gamma,
    const float* __restrict__ beta,
    float* __restrict__ out)
{
    const int row = blockIdx.x;
    const int tid = threadIdx.x;

    float4 acc = *(const float4*)&out[(size_t)row * 1024 + tid * 4];

    float s  = acc.x + acc.y + acc.z + acc.w;
    float ss = acc.x * acc.x + acc.y * acc.y + acc.z * acc.z + acc.w * acc.w;
    #pragma unroll
    for (int off = 32; off > 0; off >>= 1) {
        s  += __shfl_down(s,  off, 64);
        ss += __shfl_down(ss, off, 64);
    }

    __shared__ float red[8];
    const int wid = tid >> 6, lane = tid & 63;
    if (lane == 0) { red[wid] = s; red[4 + wid] = ss; }
    __syncthreads();

    const float S   = red[0] + red[1] + red[2] + red[3];
    const float SS  = red[4] + red[5] + red[6] + red[7];
    const float mu  = S * (1.0f / 1024.0f);
    const float var = SS * (1.0f / 1024.0f) - mu * mu;
    const float rstd = rsqrtf(var + LN_EPS);

    const float4 g = *(const float4*)&gamma[tid * 4];
    const float4 b = *(const float4*)&beta[tid * 4];
    floatx4 o;
    o[0] = (acc.x - mu) * rstd * g.x + b.x;
    o[1] = (acc.y - mu) * rstd * g.y + b.y;
    o[2] = (acc.z - mu) * rstd * g.z + b.z;
    o[3] = (acc.w - mu) * rstd * g.w + b.w;
    __builtin_nontemporal_store(o, (floatx4*)&out[(size_t)row * 1024 + tid * 4]);
}

extern "C" void kernel_launch(void* const* d_in, const int* in_sizes, int n_in,
                              void* d_out, int out_size, void* d_ws, size_t ws_size,
                              hipStream_t stream) {
    const int*   ids      = (const int*)d_in[0];
    const float* byte_emb = (const float*)d_in[1];
    const float* pos_emb  = (const float*)d_in[2];
    const float* up_w     = (const float*)d_in[3];
    const float* up_b     = (const float*)d_in[4];
    const float* gamma    = (const float*)d_in[5];
    const float* beta     = (const float*)d_in[6];
    float* out = (float*)d_out;

    // ws: wb 1MB | bb 0.25MB | posT 8MB | tableA ~4.2MB | e_pre 8MB
    unsigned short* wb     = (unsigned short*)d_ws;
    unsigned short* bb     = wb + (size_t)1024 * 512;
    unsigned short* posT   = bb + (size_t)256 * 512;
    unsigned short* tableA = posT + (size_t)16 * 512 * 512;
    unsigned short* e_pre  = tableA + (size_t)16 * TA_P_STRIDE;

    const int rows = in_sizes[0] / 16;   // 8192

    k_prep<<<1680, 256, 0, stream>>>(up_w, byte_emb, pos_emb, wb, bb, tableA, posT);

    dim3 g1(4, 2, 16);
    k1_97<<<g1, 256, 0, stream>>>(bb, posT, tableA);

    k_gather<<<rows / 4, 256, 0, stream>>>(ids, tableA, e_pre);

    dim3 g2(8, 64);
    k_up97<<<g2, 256, 0, stream>>>(e_pre, wb, up_b, out);

    k_ln<<<rows, 256, 0, stream>>>(gamma, beta, out);
}

// Round 13
// 55.366 us; speedup vs baseline: 2.4160x; 1.0605x over previous
//
#include <hip/hip_runtime.h>
#include <hip/hip_bf16.h>

#define LN_EPS 1e-5f

typedef __attribute__((ext_vector_type(8))) short short8;
typedef __attribute__((ext_vector_type(4))) float floatx4;
typedef __attribute__((ext_vector_type(4))) unsigned int uintx4;

static __device__ __forceinline__ unsigned int f2bfu(float f) {
    __hip_bfloat16 h = __float2bfloat16(f);
    return (unsigned int)__builtin_bit_cast(unsigned short, h);
}
static __device__ __forceinline__ float bf2f(unsigned short u) {
    return __builtin_bit_cast(float, (unsigned int)u << 16);
}

// async global->LDS, 16B per lane: LDS dest = wave-uniform base + lane*16,
// global src = per-lane address (m03/m97/m104 semantics).
static __device__ __forceinline__ void gload_lds16(const void* g, void* l) {
    __builtin_amdgcn_global_load_lds(
        (const __attribute__((address_space(1))) void*)g,
        (__attribute__((address_space(3))) void*)l, 16, 0, 0);
}

#define TA_P_STRIDE (257 * 512)   // tableA: [16][257][512] bf16; row 256 = zeros

// ---------------------------------------------------------------------------
// k_prep: blocks 0..511 cast up_w -> wb; 512..639 cast byte_emb -> bb;
// 640..655 zero tableA pad rows; 656..1679 transpose-cast pos_emb -> posT.
// ---------------------------------------------------------------------------
__global__ __launch_bounds__(256) void k_prep(
    const float* __restrict__ up_w, const float* __restrict__ byte_emb,
    const float* __restrict__ pos_emb,
    unsigned short* __restrict__ wb, unsigned short* __restrict__ bb,
    unsigned short* __restrict__ T, unsigned short* __restrict__ PT)
{
    const int b = blockIdx.x;
    if (b < 640) {
        const float* src;
        unsigned short* dst;
        int idx;
        if (b < 512) { src = up_w;     dst = wb; idx = (b * 256 + threadIdx.x) * 4; }
        else         { src = byte_emb; dst = bb; idx = ((b - 512) * 256 + threadIdx.x) * 4; }
        const float4 v = *(const float4*)&src[idx];
        ushort4 o;
        o.x = (unsigned short)f2bfu(v.x); o.y = (unsigned short)f2bfu(v.y);
        o.z = (unsigned short)f2bfu(v.z); o.w = (unsigned short)f2bfu(v.w);
        *(ushort4*)&dst[idx] = o;
    } else if (b < 656) {
        const int p = b - 640;
        if (threadIdx.x < 128) {
            ushort4 z; z.x = z.y = z.z = z.w = 0;
            *(ushort4*)&T[(size_t)p * TA_P_STRIDE + 256 * 512 + threadIdx.x * 4] = z;
        }
    } else {
        // transpose-cast: pos_emb [p][i][j] f32 -> posT [p][j][i] bf16
        const int idx = b - 656;
        const int j0 = (idx & 7) * 64;
        const int i0 = ((idx >> 3) & 7) * 64;
        const int p  = idx >> 6;
        const float* __restrict__ Pp = pos_emb + (size_t)p * 512 * 512;
        unsigned short* __restrict__ Tp = PT + (size_t)p * 512 * 512;

        __shared__ float S[64][65];
        const int r  = threadIdx.x >> 2;
        const int c0 = (threadIdx.x & 3) * 16;

        #pragma unroll
        for (int c = 0; c < 16; c += 4) {
            const float4 v = *(const float4*)&Pp[(size_t)(i0 + r) * 512 + j0 + c0 + c];
            S[r][c0 + c + 0] = v.x;
            S[r][c0 + c + 1] = v.y;
            S[r][c0 + c + 2] = v.z;
            S[r][c0 + c + 3] = v.w;
        }
        __syncthreads();

        #pragma unroll
        for (int h = 0; h < 2; ++h) {
            short8 o;
            #pragma unroll
            for (int k = 0; k < 8; ++k)
                o[k] = (short)f2bfu(S[c0 + h * 8 + k][r]);
            *(short8*)&Tp[(size_t)(j0 + r) * 512 + i0 + c0 + h * 8] = o;
        }
    }
}

// ---------------------------------------------------------------------------
// gload_lds 2-phase GEMM template. Block 256 thr = 4 waves (2x2), BM=BN=128,
// BK=64, operands K-major (row stride 512). LDS: 2 buffers x (A 16KB + B 16KB)
// = 64KB, LINEAR layout. Per iter: STAGE(next buf), COMPUTE(cur buf), ONE
// __syncthreads. Epilogue: Cst LDS staging -> full-row coalesced stores.
// ---------------------------------------------------------------------------
#define GEMM_PROLOG()                                                          \
    __shared__ __align__(16) unsigned short SMEM[32768]; /* 64 KB */           \
    float (*Cst)[132] = (float(*)[132])SMEM;                                   \
    const int tid = threadIdx.x;                                               \
    const int w   = tid >> 6, lane = tid & 63;                                 \
    const int lr  = lane & 15, lg = lane >> 4, lk = lg * 8;                    \
    const int wr  = w >> 1, wc = w & 1;                                        \
    const int crow = lane >> 3, ccol = (lane & 7) * 8;                         \
    floatx4 acc[4][4] = {};

#define GEMM_STAGE(b, kt) do {                                                 \
    unsigned short* Ab = SMEM + (b) * 16384;                                   \
    unsigned short* Bb = Ab + 8192;                                            \
    _Pragma("unroll")                                                          \
    for (int ci = 0; ci < 4; ++ci) {                                           \
        const int c = w + ci * 4;                                              \
        gload_lds16(&Ag[(size_t)(c * 8 + crow) * 512 + (kt) * 64 + ccol],      \
                    &Ab[c * 512]);                                             \
        gload_lds16(&Bg[(size_t)(c * 8 + crow) * 512 + (kt) * 64 + ccol],      \
                    &Bb[c * 512]);                                             \
    }                                                                          \
} while (0)

#define GEMM_COMPUTE(b) do {                                                   \
    const unsigned short* As = SMEM + (b) * 16384;                             \
    const unsigned short* Bs = As + 8192;                                      \
    _Pragma("unroll")                                                          \
    for (int kk = 0; kk < 2; ++kk) {                                           \
        short8 af[4], bf[4];                                                   \
        _Pragma("unroll")                                                      \
        for (int mf = 0; mf < 4; ++mf)                                         \
            af[mf] = *(const short8*)&As[(wr * 64 + mf * 16 + lr) * 64 + kk * 32 + lk]; \
        _Pragma("unroll")                                                      \
        for (int nf = 0; nf < 4; ++nf)                                         \
            bf[nf] = *(const short8*)&Bs[(wc * 64 + nf * 16 + lr) * 64 + kk * 32 + lk]; \
        _Pragma("unroll")                                                      \
        for (int mf = 0; mf < 4; ++mf)                                         \
            _Pragma("unroll")                                                  \
            for (int nf = 0; nf < 4; ++nf)                                     \
                acc[mf][nf] = __builtin_amdgcn_mfma_f32_16x16x32_bf16(         \
                    af[mf], bf[nf], acc[mf][nf], 0, 0, 0);                     \
    }                                                                          \
} while (0)

#define GEMM_MAIN()                                                            \
    GEMM_STAGE(0, 0);                                                          \
    __syncthreads();                                                           \
    {                                                                          \
        int buf = 0;                                                           \
        for (int kt = 0; kt < 8; ++kt) {                                       \
            if (kt < 7) GEMM_STAGE(buf ^ 1, kt + 1);                           \
            GEMM_COMPUTE(buf);                                                 \
            __syncthreads();                                                   \
            buf ^= 1;                                                          \
        }                                                                      \
    }

// Stage one 32-row quarter of acc (+per-col add 'addv') into Cst.
#define CST_STAGE(qr, addv)                                                    \
    if (wr == ((qr) >> 1)) {                                                   \
        _Pragma("unroll")                                                      \
        for (int mfq = 0; mfq < 2; ++mfq) {                                    \
            const int mf = ((qr) & 1) * 2 + mfq;                               \
            _Pragma("unroll")                                                  \
            for (int nf = 0; nf < 4; ++nf)                                     \
                _Pragma("unroll")                                              \
                for (int q = 0; q < 4; ++q)                                    \
                    Cst[mfq * 16 + lg * 4 + q][wc * 64 + nf * 16 + lr]         \
                        = acc[mf][nf][q] + addv;                               \
        }                                                                      \
    }

// ---------------------------------------------------------------------------
// k1_97: tableA[p][m][j] = sum_i bb[m][i] * posT[p][j][i]  (bf16 out)
// Grid (4 j-tiles, 2 m-tiles, 16 p) = 128 blocks.
// ---------------------------------------------------------------------------
__global__ __launch_bounds__(256) void k1_97(
    const unsigned short* __restrict__ A,   // bb [256][512]
    const unsigned short* __restrict__ PT,  // posT [16][512][512] ([p][j][i])
    unsigned short* __restrict__ T)         // tableA [16][257][512]
{
    const int p  = blockIdx.z;
    const int n0 = blockIdx.x * 128;   // j
    const int m0 = blockIdx.y * 128;   // m
    const unsigned short* __restrict__ Ag = A + (size_t)m0 * 512;
    const unsigned short* __restrict__ Bg = PT + (size_t)p * 512 * 512 + (size_t)n0 * 512;
    unsigned short* __restrict__ Tp = T + (size_t)p * TA_P_STRIDE;

    GEMM_PROLOG();
    GEMM_MAIN();
    __syncthreads();   // all LDS frag reads done; safe to alias Cst

    #pragma unroll
    for (int qr = 0; qr < 4; ++qr) {
        CST_STAGE(qr, 0.0f);
        __syncthreads();
        #pragma unroll
        for (int pass = 0; pass < 2; ++pass) {
            const int row = pass * 16 + (tid >> 4);
            const int c8  = (tid & 15) * 8;
            uint4 o;
            o.x = f2bfu(Cst[row][c8 + 0]) | (f2bfu(Cst[row][c8 + 1]) << 16);
            o.y = f2bfu(Cst[row][c8 + 2]) | (f2bfu(Cst[row][c8 + 3]) << 16);
            o.z = f2bfu(Cst[row][c8 + 4]) | (f2bfu(Cst[row][c8 + 5]) << 16);
            o.w = f2bfu(Cst[row][c8 + 6]) | (f2bfu(Cst[row][c8 + 7]) << 16);
            *(uint4*)&Tp[(size_t)(m0 + qr * 32 + row) * 512 + n0 + c8] = o;
        }
        __syncthreads();
    }
}

// ---------------------------------------------------------------------------
// k_up97: e2[m][d] = bf16( sum_j e_pre[m][j]*wb[d][j] + up_b[d] )  (NT bf16)
// Grid (8 d-tiles, 64 m-tiles) = 512 blocks, XCD-swizzled (T1).
// ---------------------------------------------------------------------------
__global__ __launch_bounds__(256) void k_up97(
    const unsigned short* __restrict__ Aep,  // e_pre [8192][512]
    const unsigned short* __restrict__ Wb,   // up_w  [1024][512]
    const float* __restrict__ up_b,
    unsigned short* __restrict__ e2)         // [8192][1024] bf16
{
    // XCD swizzle: nwg=512, 8 XCDs. XCD x gets m-tiles 8x..8x+7, all n-tiles.
    const int bid = blockIdx.y * 8 + blockIdx.x;
    const int swz = (bid & 7) * 64 + (bid >> 3);
    const int n0 = (swz & 7) * 128;
    const int m0 = (swz >> 3) * 128;
    const unsigned short* __restrict__ Ag = Aep + (size_t)m0 * 512;
    const unsigned short* __restrict__ Bg = Wb + (size_t)n0 * 512;

    GEMM_PROLOG();
    GEMM_MAIN();
    __syncthreads();   // all LDS frag reads done; safe to alias Cst

    float biasv[4];
    #pragma unroll
    for (int nf = 0; nf < 4; ++nf) biasv[nf] = up_b[n0 + wc * 64 + nf * 16 + lr];

    #pragma unroll
    for (int qr = 0; qr < 4; ++qr) {
        CST_STAGE(qr, biasv[nf]);
        __syncthreads();
        #pragma unroll
        for (int pass = 0; pass < 2; ++pass) {
            const int row = pass * 16 + (tid >> 4);
            const int c8  = (tid & 15) * 8;
            uintx4 o;
            o[0] = f2bfu(Cst[row][c8 + 0]) | (f2bfu(Cst[row][c8 + 1]) << 16);
            o[1] = f2bfu(Cst[row][c8 + 2]) | (f2bfu(Cst[row][c8 + 3]) << 16);
            o[2] = f2bfu(Cst[row][c8 + 4]) | (f2bfu(Cst[row][c8 + 5]) << 16);
            o[3] = f2bfu(Cst[row][c8 + 6]) | (f2bfu(Cst[row][c8 + 7]) << 16);
            __builtin_nontemporal_store(
                o, (uintx4*)&e2[(size_t)(m0 + qr * 32 + row) * 1024 + n0 + c8]);
        }
        __syncthreads();
    }
}

// ---------------------------------------------------------------------------
// k_gather: e_pre[row][j] = sum_p tableA[p][idr(row,p)][j]  (fp32 accum, bf16
// out). One wave per row, 4 rows/block. Branchless via pad row.
// ---------------------------------------------------------------------------
__global__ __launch_bounds__(256) void k_gather(
    const int* __restrict__ ids,
    const unsigned short* __restrict__ T,
    unsigned short* __restrict__ e_pre)
{
    const int row  = blockIdx.x * 4 + (threadIdx.x >> 6);
    const int lane = threadIdx.x & 63;
    const int* __restrict__ idr = ids + row * 16;

    float acc[8] = {};
    #pragma unroll
    for (int p = 0; p < 16; ++p) {
        const int id = idr[p];
        const unsigned int off = (unsigned int)((p * 257 + (id < 0 ? 256 : id)) * 512);
        const short8 v = *(const short8*)&T[off + lane * 8];
        #pragma unroll
        for (int j = 0; j < 8; ++j)
            acc[j] += bf2f((unsigned short)v[j]);
    }
    short8 r;
    #pragma unroll
    for (int j = 0; j < 8; ++j) r[j] = (short)f2bfu(acc[j]);
    *(short8*)&e_pre[(size_t)row * 512 + lane * 8] = r;
}

// ---------------------------------------------------------------------------
// k_ln: out[row][:] = LN(e2[row][:]) * gamma + beta.  Block per row, 256 thr,
// each thread owns 4 consecutive d. Reads bf16 e2, writes f32 out (NT).
// ---------------------------------------------------------------------------
__global__ __launch_bounds__(256) void k_ln(
    const unsigned short* __restrict__ e2,   // [rows][1024] bf16
    const float* __restrict__ gamma,
    const float* __restrict__ beta,
    float* __restrict__ out)                 // [rows][1024] f32
{
    const int row = blockIdx.x;
    const int tid = threadIdx.x;

    const uint2 u = *(const uint2*)&e2[(size_t)row * 1024 + tid * 4];
    float a0 = bf2f((unsigned short)(u.x & 0xffffu));
    float a1 = bf2f((unsigned short)(u.x >> 16));
    float a2 = bf2f((unsigned short)(u.y & 0xffffu));
    float a3 = bf2f((unsigned short)(u.y >> 16));

    float s  = a0 + a1 + a2 + a3;
    float ss = a0 * a0 + a1 * a1 + a2 * a2 + a3 * a3;
    #pragma unroll
    for (int off = 32; off > 0; off >>= 1) {
        s  += __shfl_down(s,  off, 64);
        ss += __shfl_down(ss, off, 64);
    }

    __shared__ float red[8];
    const int wid = tid >> 6, lane = tid & 63;
    if (lane == 0) { red[wid] = s; red[4 + wid] = ss; }
    __syncthreads();

    const float S   = red[0] + red[1] + red[2] + red[3];
    const float SS  = red[4] + red[5] + red[6] + red[7];
    const float mu  = S * (1.0f / 1024.0f);
    const float var = SS * (1.0f / 1024.0f) - mu * mu;
    const float rstd = rsqrtf(var + LN_EPS);

    const float4 g = *(const float4*)&gamma[tid * 4];
    const float4 b = *(const float4*)&beta[tid * 4];
    floatx4 o;
    o[0] = (a0 - mu) * rstd * g.x + b.x;
    o[1] = (a1 - mu) * rstd * g.y + b.y;
    o[2] = (a2 - mu) * rstd * g.z + b.z;
    o[3] = (a3 - mu) * rstd * g.w + b.w;
    __builtin_nontemporal_store(o, (floatx4*)&out[(size_t)row * 1024 + tid * 4]);
}

extern "C" void kernel_launch(void* const* d_in, const int* in_sizes, int n_in,
                              void* d_out, int out_size, void* d_ws, size_t ws_size,
                              hipStream_t stream) {
    const int*   ids      = (const int*)d_in[0];
    const float* byte_emb = (const float*)d_in[1];
    const float* pos_emb  = (const float*)d_in[2];
    const float* up_w     = (const float*)d_in[3];
    const float* up_b     = (const float*)d_in[4];
    const float* gamma    = (const float*)d_in[5];
    const float* beta     = (const float*)d_in[6];
    float* out = (float*)d_out;

    // ws: wb 1MB | bb 0.25MB | posT 8MB | tableA ~4.2MB | e_pre 8MB | e2 16MB
    unsigned short* wb     = (unsigned short*)d_ws;
    unsigned short* bb     = wb + (size_t)1024 * 512;
    unsigned short* posT   = bb + (size_t)256 * 512;
    unsigned short* tableA = posT + (size_t)16 * 512 * 512;
    unsigned short* e_pre  = tableA + (size_t)16 * TA_P_STRIDE;
    unsigned short* e2     = e_pre + (size_t)8192 * 512;

    const int rows = in_sizes[0] / 16;   // 8192

    k_prep<<<1680, 256, 0, stream>>>(up_w, byte_emb, pos_emb, wb, bb, tableA, posT);

    dim3 g1(4, 2, 16);
    k1_97<<<g1, 256, 0, stream>>>(bb, posT, tableA);

    k_gather<<<rows / 4, 256, 0, stream>>>(ids, tableA, e_pre);

    dim3 g2(8, 64);
    k_up97<<<g2, 256, 0, stream>>>(e_pre, wb, up_b, e2);

    k_ln<<<rows, 256, 0, stream>>>(e2, gamma, beta, out);
}

// Round 14
// 53.490 us; speedup vs baseline: 2.5007x; 1.0351x over previous
//
#include <hip/hip_runtime.h>
#include <hip/hip_bf16.h>

#define LN_EPS 1e-5f

typedef __attribute__((ext_vector_type(8))) short short8;
typedef __attribute__((ext_vector_type(4))) float floatx4;
typedef __attribute__((ext_vector_type(4))) unsigned int uintx4;

static __device__ __forceinline__ unsigned int f2bfu(float f) {
    __hip_bfloat16 h = __float2bfloat16(f);
    return (unsigned int)__builtin_bit_cast(unsigned short, h);
}
static __device__ __forceinline__ float bf2f(unsigned short u) {
    return __builtin_bit_cast(float, (unsigned int)u << 16);
}

// async global->LDS, 16B per lane: LDS dest = wave-uniform base + lane*16,
// global src = per-lane address (m03/m97/m104 semantics).
static __device__ __forceinline__ void gload_lds16(const void* g, void* l) {
    __builtin_amdgcn_global_load_lds(
        (const __attribute__((address_space(1))) void*)g,
        (__attribute__((address_space(3))) void*)l, 16, 0, 0);
}

#define TA_P_STRIDE (257 * 512)   // tableA: [16][257][512] bf16; row 256 = zeros

// ---------------------------------------------------------------------------
// k_prep: blocks 0..511 cast up_w -> wb; 512..639 cast byte_emb -> bb;
// 640..655 zero tableA pad rows; 656..1679 transpose-cast pos_emb -> posT.
// ---------------------------------------------------------------------------
__global__ __launch_bounds__(256) void k_prep(
    const float* __restrict__ up_w, const float* __restrict__ byte_emb,
    const float* __restrict__ pos_emb,
    unsigned short* __restrict__ wb, unsigned short* __restrict__ bb,
    unsigned short* __restrict__ T, unsigned short* __restrict__ PT)
{
    const int b = blockIdx.x;
    if (b < 640) {
        const float* src;
        unsigned short* dst;
        int idx;
        if (b < 512) { src = up_w;     dst = wb; idx = (b * 256 + threadIdx.x) * 4; }
        else         { src = byte_emb; dst = bb; idx = ((b - 512) * 256 + threadIdx.x) * 4; }
        const float4 v = *(const float4*)&src[idx];
        ushort4 o;
        o.x = (unsigned short)f2bfu(v.x); o.y = (unsigned short)f2bfu(v.y);
        o.z = (unsigned short)f2bfu(v.z); o.w = (unsigned short)f2bfu(v.w);
        *(ushort4*)&dst[idx] = o;
    } else if (b < 656) {
        const int p = b - 640;
        if (threadIdx.x < 128) {
            ushort4 z; z.x = z.y = z.z = z.w = 0;
            *(ushort4*)&T[(size_t)p * TA_P_STRIDE + 256 * 512 + threadIdx.x * 4] = z;
        }
    } else {
        // transpose-cast: pos_emb [p][i][j] f32 -> posT [p][j][i] bf16
        const int idx = b - 656;
        const int j0 = (idx & 7) * 64;
        const int i0 = ((idx >> 3) & 7) * 64;
        const int p  = idx >> 6;
        const float* __restrict__ Pp = pos_emb + (size_t)p * 512 * 512;
        unsigned short* __restrict__ Tp = PT + (size_t)p * 512 * 512;

        __shared__ float S[64][65];
        const int r  = threadIdx.x >> 2;
        const int c0 = (threadIdx.x & 3) * 16;

        #pragma unroll
        for (int c = 0; c < 16; c += 4) {
            const float4 v = *(const float4*)&Pp[(size_t)(i0 + r) * 512 + j0 + c0 + c];
            S[r][c0 + c + 0] = v.x;
            S[r][c0 + c + 1] = v.y;
            S[r][c0 + c + 2] = v.z;
            S[r][c0 + c + 3] = v.w;
        }
        __syncthreads();

        #pragma unroll
        for (int h = 0; h < 2; ++h) {
            short8 o;
            #pragma unroll
            for (int k = 0; k < 8; ++k)
                o[k] = (short)f2bfu(S[c0 + h * 8 + k][r]);
            *(short8*)&Tp[(size_t)(j0 + r) * 512 + i0 + c0 + h * 8] = o;
        }
    }
}

// ---------------------------------------------------------------------------
// gload_lds 2-phase GEMM template. Block 256 thr = 4 waves (2x2), BM=BN=128,
// BK=64, operands K-major (row stride 512). LDS: 2 buffers x (A 16KB + B 16KB)
// = 64KB, LINEAR layout. Per iter: STAGE(next buf), COMPUTE(cur buf), ONE
// __syncthreads. Epilogue: Cst LDS staging -> full-row coalesced stores.
// ---------------------------------------------------------------------------
#define GEMM_PROLOG()                                                          \
    __shared__ __align__(16) unsigned short SMEM[32768]; /* 64 KB */           \
    float (*Cst)[132] = (float(*)[132])SMEM;                                   \
    const int tid = threadIdx.x;                                               \
    const int w   = tid >> 6, lane = tid & 63;                                 \
    const int lr  = lane & 15, lg = lane >> 4, lk = lg * 8;                    \
    const int wr  = w >> 1, wc = w & 1;                                        \
    const int crow = lane >> 3, ccol = (lane & 7) * 8;                         \
    floatx4 acc[4][4] = {};

#define GEMM_STAGE(b, kt) do {                                                 \
    unsigned short* Ab = SMEM + (b) * 16384;                                   \
    unsigned short* Bb = Ab + 8192;                                            \
    _Pragma("unroll")                                                          \
    for (int ci = 0; ci < 4; ++ci) {                                           \
        const int c = w + ci * 4;                                              \
        gload_lds16(&Ag[(size_t)(c * 8 + crow) * 512 + (kt) * 64 + ccol],      \
                    &Ab[c * 512]);                                             \
        gload_lds16(&Bg[(size_t)(c * 8 + crow) * 512 + (kt) * 64 + ccol],      \
                    &Bb[c * 512]);                                             \
    }                                                                          \
} while (0)

#define GEMM_COMPUTE(b) do {                                                   \
    const unsigned short* As = SMEM + (b) * 16384;                             \
    const unsigned short* Bs = As + 8192;                                      \
    _Pragma("unroll")                                                          \
    for (int kk = 0; kk < 2; ++kk) {                                           \
        short8 af[4], bf[4];                                                   \
        _Pragma("unroll")                                                      \
        for (int mf = 0; mf < 4; ++mf)                                         \
            af[mf] = *(const short8*)&As[(wr * 64 + mf * 16 + lr) * 64 + kk * 32 + lk]; \
        _Pragma("unroll")                                                      \
        for (int nf = 0; nf < 4; ++nf)                                         \
            bf[nf] = *(const short8*)&Bs[(wc * 64 + nf * 16 + lr) * 64 + kk * 32 + lk]; \
        _Pragma("unroll")                                                      \
        for (int mf = 0; mf < 4; ++mf)                                         \
            _Pragma("unroll")                                                  \
            for (int nf = 0; nf < 4; ++nf)                                     \
                acc[mf][nf] = __builtin_amdgcn_mfma_f32_16x16x32_bf16(         \
                    af[mf], bf[nf], acc[mf][nf], 0, 0, 0);                     \
    }                                                                          \
} while (0)

#define GEMM_MAIN()                                                            \
    GEMM_STAGE(0, 0);                                                          \
    __syncthreads();                                                           \
    {                                                                          \
        int buf = 0;                                                           \
        for (int kt = 0; kt < 8; ++kt) {                                       \
            if (kt < 7) GEMM_STAGE(buf ^ 1, kt + 1);                           \
            GEMM_COMPUTE(buf);                                                 \
            __syncthreads();                                                   \
            buf ^= 1;                                                          \
        }                                                                      \
    }

// Stage one 32-row quarter of acc (+per-col add 'addv') into Cst.
#define CST_STAGE(qr, addv)                                                    \
    if (wr == ((qr) >> 1)) {                                                   \
        _Pragma("unroll")                                                      \
        for (int mfq = 0; mfq < 2; ++mfq) {                                    \
            const int mf = ((qr) & 1) * 2 + mfq;                               \
            _Pragma("unroll")                                                  \
            for (int nf = 0; nf < 4; ++nf)                                     \
                _Pragma("unroll")                                              \
                for (int q = 0; q < 4; ++q)                                    \
                    Cst[mfq * 16 + lg * 4 + q][wc * 64 + nf * 16 + lr]         \
                        = acc[mf][nf][q] + addv;                               \
        }                                                                      \
    }

// ---------------------------------------------------------------------------
// k1_97: tableA[p][m][j] = sum_i bb[m][i] * posT[p][j][i]  (bf16 out)
// Grid (4 j-tiles, 2 m-tiles, 16 p) = 128 blocks.
// ---------------------------------------------------------------------------
__global__ __launch_bounds__(256) void k1_97(
    const unsigned short* __restrict__ A,   // bb [256][512]
    const unsigned short* __restrict__ PT,  // posT [16][512][512] ([p][j][i])
    unsigned short* __restrict__ T)         // tableA [16][257][512]
{
    const int p  = blockIdx.z;
    const int n0 = blockIdx.x * 128;   // j
    const int m0 = blockIdx.y * 128;   // m
    const unsigned short* __restrict__ Ag = A + (size_t)m0 * 512;
    const unsigned short* __restrict__ Bg = PT + (size_t)p * 512 * 512 + (size_t)n0 * 512;
    unsigned short* __restrict__ Tp = T + (size_t)p * TA_P_STRIDE;

    GEMM_PROLOG();
    GEMM_MAIN();
    __syncthreads();   // all LDS frag reads done; safe to alias Cst

    #pragma unroll
    for (int qr = 0; qr < 4; ++qr) {
        CST_STAGE(qr, 0.0f);
        __syncthreads();
        #pragma unroll
        for (int pass = 0; pass < 2; ++pass) {
            const int row = pass * 16 + (tid >> 4);
            const int c8  = (tid & 15) * 8;
            uint4 o;
            o.x = f2bfu(Cst[row][c8 + 0]) | (f2bfu(Cst[row][c8 + 1]) << 16);
            o.y = f2bfu(Cst[row][c8 + 2]) | (f2bfu(Cst[row][c8 + 3]) << 16);
            o.z = f2bfu(Cst[row][c8 + 4]) | (f2bfu(Cst[row][c8 + 5]) << 16);
            o.w = f2bfu(Cst[row][c8 + 6]) | (f2bfu(Cst[row][c8 + 7]) << 16);
            *(uint4*)&Tp[(size_t)(m0 + qr * 32 + row) * 512 + n0 + c8] = o;
        }
        __syncthreads();
    }
}

// ---------------------------------------------------------------------------
// k_up97: e2[m][d] = bf16( sum_j e_pre[m][j]*wb[d][j] + up_b[d] )
// Grid (8 d-tiles, 64 m-tiles) = 512 blocks, XCD-swizzled: XCD x owns
// m-tiles 8x..8x+7 (rows x*1024..x*1024+1023). e2 stored CACHED (re-read by
// k_ln on the same XCD).
// ---------------------------------------------------------------------------
__global__ __launch_bounds__(256) void k_up97(
    const unsigned short* __restrict__ Aep,  // e_pre [8192][512]
    const unsigned short* __restrict__ Wb,   // up_w  [1024][512]
    const float* __restrict__ up_b,
    unsigned short* __restrict__ e2)         // [8192][1024] bf16
{
    const int bid = blockIdx.y * 8 + blockIdx.x;
    const int swz = (bid & 7) * 64 + (bid >> 3);
    const int n0 = (swz & 7) * 128;
    const int m0 = (swz >> 3) * 128;
    const unsigned short* __restrict__ Ag = Aep + (size_t)m0 * 512;
    const unsigned short* __restrict__ Bg = Wb + (size_t)n0 * 512;

    GEMM_PROLOG();
    GEMM_MAIN();
    __syncthreads();   // all LDS frag reads done; safe to alias Cst

    float biasv[4];
    #pragma unroll
    for (int nf = 0; nf < 4; ++nf) biasv[nf] = up_b[n0 + wc * 64 + nf * 16 + lr];

    #pragma unroll
    for (int qr = 0; qr < 4; ++qr) {
        CST_STAGE(qr, biasv[nf]);
        __syncthreads();
        #pragma unroll
        for (int pass = 0; pass < 2; ++pass) {
            const int row = pass * 16 + (tid >> 4);
            const int c8  = (tid & 15) * 8;
            uint4 o;
            o.x = f2bfu(Cst[row][c8 + 0]) | (f2bfu(Cst[row][c8 + 1]) << 16);
            o.y = f2bfu(Cst[row][c8 + 2]) | (f2bfu(Cst[row][c8 + 3]) << 16);
            o.z = f2bfu(Cst[row][c8 + 4]) | (f2bfu(Cst[row][c8 + 5]) << 16);
            o.w = f2bfu(Cst[row][c8 + 6]) | (f2bfu(Cst[row][c8 + 7]) << 16);
            *(uint4*)&e2[(size_t)(m0 + qr * 32 + row) * 1024 + n0 + c8] = o;
        }
        __syncthreads();
    }
}

// ---------------------------------------------------------------------------
// k_gather: e_pre[row][j] = sum_p tableA[p][idr(row,p)][j].
// Block b (XCD b&7) handles rows (b&7)*1024 + (b>>3)*4 + {0..3} so e_pre rows
// are written on the XCD whose k_up97 blocks will read them (L2-local).
// All 16 table rows preloaded into regs (indep loads), then summed.
// ---------------------------------------------------------------------------
__global__ __launch_bounds__(256) void k_gather(
    const int* __restrict__ ids,
    const unsigned short* __restrict__ T,
    unsigned short* __restrict__ e_pre)
{
    const int b    = blockIdx.x;
    const int row  = (b & 7) * 1024 + (b >> 3) * 4 + (threadIdx.x >> 6);
    const int lane = threadIdx.x & 63;
    const int* __restrict__ idr = ids + row * 16;

    uint4 u[16];
    #pragma unroll
    for (int p = 0; p < 16; ++p) {
        const int id = idr[p];
        const unsigned int off = (unsigned int)((p * 257 + (id < 0 ? 256 : id)) * 512);
        u[p] = *(const uint4*)&T[off + lane * 8];
    }

    float acc[8] = {};
    #pragma unroll
    for (int p = 0; p < 16; ++p) {
        acc[0] += bf2f((unsigned short)(u[p].x & 0xffffu));
        acc[1] += bf2f((unsigned short)(u[p].x >> 16));
        acc[2] += bf2f((unsigned short)(u[p].y & 0xffffu));
        acc[3] += bf2f((unsigned short)(u[p].y >> 16));
        acc[4] += bf2f((unsigned short)(u[p].z & 0xffffu));
        acc[5] += bf2f((unsigned short)(u[p].z >> 16));
        acc[6] += bf2f((unsigned short)(u[p].w & 0xffffu));
        acc[7] += bf2f((unsigned short)(u[p].w >> 16));
    }

    uint4 r;
    r.x = f2bfu(acc[0]) | (f2bfu(acc[1]) << 16);
    r.y = f2bfu(acc[2]) | (f2bfu(acc[3]) << 16);
    r.z = f2bfu(acc[4]) | (f2bfu(acc[5]) << 16);
    r.w = f2bfu(acc[6]) | (f2bfu(acc[7]) << 16);
    *(uint4*)&e_pre[(size_t)row * 512 + lane * 8] = r;
}

// ---------------------------------------------------------------------------
// k_ln: out[row][:] = LN(e2[row][:]) * gamma + beta.  Block b -> row
// (b&7)*1024 + (b>>3): same XCD as the k_up97 block that wrote the row ->
// e2 read is an XCD-local L2 hit. out written NT (never re-read).
// ---------------------------------------------------------------------------
__global__ __launch_bounds__(256) void k_ln(
    const unsigned short* __restrict__ e2,   // [rows][1024] bf16
    const float* __restrict__ gamma,
    const float* __restrict__ beta,
    float* __restrict__ out)                 // [rows][1024] f32
{
    const int b   = blockIdx.x;
    const int row = (b & 7) * 1024 + (b >> 3);
    const int tid = threadIdx.x;

    const uint2 u = *(const uint2*)&e2[(size_t)row * 1024 + tid * 4];
    float a0 = bf2f((unsigned short)(u.x & 0xffffu));
    float a1 = bf2f((unsigned short)(u.x >> 16));
    float a2 = bf2f((unsigned short)(u.y & 0xffffu));
    float a3 = bf2f((unsigned short)(u.y >> 16));

    float s  = a0 + a1 + a2 + a3;
    float ss = a0 * a0 + a1 * a1 + a2 * a2 + a3 * a3;
    #pragma unroll
    for (int off = 32; off > 0; off >>= 1) {
        s  += __shfl_down(s,  off, 64);
        ss += __shfl_down(ss, off, 64);
    }

    __shared__ float red[8];
    const int wid = tid >> 6, lane = tid & 63;
    if (lane == 0) { red[wid] = s; red[4 + wid] = ss; }
    __syncthreads();

    const float S   = red[0] + red[1] + red[2] + red[3];
    const float SS  = red[4] + red[5] + red[6] + red[7];
    const float mu  = S * (1.0f / 1024.0f);
    const float var = SS * (1.0f / 1024.0f) - mu * mu;
    const float rstd = rsqrtf(var + LN_EPS);

    const float4 g = *(const float4*)&gamma[tid * 4];
    const float4 bt = *(const float4*)&beta[tid * 4];
    floatx4 o;
    o[0] = (a0 - mu) * rstd * g.x + bt.x;
    o[1] = (a1 - mu) * rstd * g.y + bt.y;
    o[2] = (a2 - mu) * rstd * g.z + bt.z;
    o[3] = (a3 - mu) * rstd * g.w + bt.w;
    __builtin_nontemporal_store(o, (floatx4*)&out[(size_t)row * 1024 + tid * 4]);
}

extern "C" void kernel_launch(void* const* d_in, const int* in_sizes, int n_in,
                              void* d_out, int out_size, void* d_ws, size_t ws_size,
                              hipStream_t stream) {
    const int*   ids      = (const int*)d_in[0];
    const float* byte_emb = (const float*)d_in[1];
    const float* pos_emb  = (const float*)d_in[2];
    const float* up_w     = (const float*)d_in[3];
    const float* up_b     = (const float*)d_in[4];
    const float* gamma    = (const float*)d_in[5];
    const float* beta     = (const float*)d_in[6];
    float* out = (float*)d_out;

    // ws: wb 1MB | bb 0.25MB | posT 8MB | tableA ~4.2MB | e_pre 8MB | e2 16MB
    unsigned short* wb     = (unsigned short*)d_ws;
    unsigned short* bb     = wb + (size_t)1024 * 512;
    unsigned short* posT   = bb + (size_t)256 * 512;
    unsigned short* tableA = posT + (size_t)16 * 512 * 512;
    unsigned short* e_pre  = tableA + (size_t)16 * TA_P_STRIDE;
    unsigned short* e2     = e_pre + (size_t)8192 * 512;

    const int rows = in_sizes[0] / 16;   // 8192

    k_prep<<<1680, 256, 0, stream>>>(up_w, byte_emb, pos_emb, wb, bb, tableA, posT);

    dim3 g1(4, 2, 16);
    k1_97<<<g1, 256, 0, stream>>>(bb, posT, tableA);

    k_gather<<<rows / 4, 256, 0, stream>>>(ids, tableA, e_pre);

    dim3 g2(8, 64);
    k_up97<<<g2, 256, 0, stream>>>(e_pre, wb, up_b, e2);

    k_ln<<<rows, 256, 0, stream>>>(e2, gamma, beta, out);
}